// Round 1
// baseline (185.927 us; speedup 1.0000x reference)
//
#include <hip/hip_runtime.h>

// Problem constants (from reference setup_inputs): B=8, G=32, A=200000.
// B and A derived from in_sizes at launch; G=32 is hard-unrolled.
#define GT_PER_IMG 32

// IoU must be bit-identical between the two kernels (exact == test against
// highest_per_gt) and must match numpy's unfused f32 arithmetic (label
// threshold decisions are exact-valued) -> contraction off.
__device__ __forceinline__ float iou_fn(float g0, float g1, float g2, float g3,
                                        float a0, float a1, float a2, float a3) {
#pragma clang fp contract(off)
    float area_g = (g2 - g0) * (g3 - g1);
    float area_a = (a2 - a0) * (a3 - a1);
    float ltx = fmaxf(g0, a0), lty = fmaxf(g1, a1);
    float rbx = fminf(g2, a2), rby = fminf(g3, a3);
    float wx = fmaxf(rbx - ltx, 0.0f), wy = fmaxf(rby - lty, 0.0f);
    float inter = wx * wy;
    float uni = area_g + area_a - inter;
    return inter > 0.0f ? inter / uni : 0.0f;
}

// Pass 1: highest_per_gt[b*G+g] = max over anchors of iou(gt[b][g], anchor).
// Grid: (chunks, B). Each thread keeps 32 running maxes; wave shuffle-reduce,
// LDS cross-wave reduce, one atomicMax per (block, g). IoU >= 0 so uint-bit
// atomicMax is order-correct; d_ws zeroed beforehand.
__global__ __launch_bounds__(256) void k_highest(const float* __restrict__ gt,
                                                 const float* __restrict__ anchors,
                                                 float* __restrict__ highest,
                                                 int A) {
#pragma clang fp contract(off)
    __shared__ float4 s_gt[GT_PER_IMG];
    __shared__ float s_red[4 * GT_PER_IMG];
    const int b = blockIdx.y;
    const int tid = threadIdx.x;
    if (tid < GT_PER_IMG) s_gt[tid] = ((const float4*)gt)[b * GT_PER_IMG + tid];
    __syncthreads();

    float lm[GT_PER_IMG];
#pragma unroll
    for (int g = 0; g < GT_PER_IMG; ++g) lm[g] = 0.0f;  // iou >= 0, 0 is identity

    const int stride = gridDim.x * 256;
    for (int a = blockIdx.x * 256 + tid; a < A; a += stride) {
        float4 an = ((const float4*)anchors)[a];
#pragma unroll
        for (int g = 0; g < GT_PER_IMG; ++g) {
            float4 gb = s_gt[g];
            float v = iou_fn(gb.x, gb.y, gb.z, gb.w, an.x, an.y, an.z, an.w);
            lm[g] = fmaxf(lm[g], v);
        }
    }

    const int lane = tid & 63, wid = tid >> 6;
#pragma unroll
    for (int g = 0; g < GT_PER_IMG; ++g) {
        float v = lm[g];
#pragma unroll
        for (int off = 32; off > 0; off >>= 1) v = fmaxf(v, __shfl_down(v, off, 64));
        if (lane == 0) s_red[wid * GT_PER_IMG + g] = v;
    }
    __syncthreads();
    if (tid < GT_PER_IMG) {
        float v = fmaxf(fmaxf(s_red[tid], s_red[GT_PER_IMG + tid]),
                        fmaxf(s_red[2 * GT_PER_IMG + tid], s_red[3 * GT_PER_IMG + tid]));
        atomicMax((unsigned int*)&highest[b * GT_PER_IMG + tid], __float_as_uint(v));
    }
}

// Pass 2: one thread per anchor; loop over images. All GT boxes (B*G float4)
// and highest_per_gt staged in LDS. Strict '>' in argmax keeps first max
// (matches jnp.argmax tie-break).
__global__ __launch_bounds__(256) void k_label(const float* __restrict__ gt,
                                               const float* __restrict__ anchors,
                                               const float* __restrict__ highest,
                                               float* __restrict__ out,
                                               int A, int B) {
#pragma clang fp contract(off)
    __shared__ float4 s_gt[256];
    __shared__ float s_hi[256];
    const int tid = threadIdx.x;
    const int NBG = B * GT_PER_IMG;  // 256 for B=8
    if (tid < NBG) {
        s_gt[tid] = ((const float4*)gt)[tid];
        s_hi[tid] = highest[tid];
    }
    __syncthreads();

    const int a = blockIdx.x * 256 + tid;
    if (a >= A) return;

    const float4 an = ((const float4*)anchors)[a];
    const float cx = 0.5f * (an.x + an.z);
    const float cy = 0.5f * (an.y + an.w);
    const float w = an.z - an.x;
    const float h = an.w - an.y;
    const size_t BA = (size_t)B * (size_t)A;

    for (int b = 0; b < B; ++b) {
        float best = -1.0f;
        int idx = 0;
        bool lq = false;
#pragma unroll
        for (int g = 0; g < GT_PER_IMG; ++g) {
            float4 gb = s_gt[b * GT_PER_IMG + g];
            float v = iou_fn(gb.x, gb.y, gb.z, gb.w, an.x, an.y, an.z, an.w);
            if (v > best) { best = v; idx = g; }
            lq |= (v == s_hi[b * GT_PER_IMG + g]);
        }

        int gl = (best >= 0.7f) ? 1 : ((best >= 0.3f) ? -1 : 0);
        int ol = (best >= 0.3f) ? 1 : ((best >= 0.1f) ? -1 : 0);
        if (lq) { gl = 1; ol = 1; }

        const float4 t = s_gt[b * GT_PER_IMG + idx];
        // deltas, reordered per d[:, [0,2,1,3]] -> (l, r, t, b)
        float d0 = (cx - t.x) / w;
        float d1 = (t.z - cx) / w;
        float d2 = (cy - t.y) / h;
        float d3 = (t.w - cy) / h;
        const bool inb = (d0 >= 0.0f) && (d1 >= 0.0f) && (d2 >= 0.0f) && (d3 >= 0.0f);
        if (!inb) { d0 = d1 = d2 = d3 = 0.0f; }
        float prod = (fminf(d0, d1) / (fmaxf(d0, d1) + 1e-12f)) *
                     (fminf(d2, d3) / (fmaxf(d2, d3) + 1e-12f));
        float cen = (prod > 0.0f) ? sqrtf(prod) : 0.0f;
        if (ol == 0) cen = 0.0f;

        const size_t o = (size_t)b * (size_t)A + (size_t)a;
        out[o] = (float)gl;                       // gt_labels
        ((float4*)(out + BA))[o] = t;             // matched_gt_boxes (16B-aligned: BA%4==0)
        out[5 * BA + o] = (float)ol;              // obj_labels
        out[6 * BA + o] = cen;                    // centerness
    }
}

extern "C" void kernel_launch(void* const* d_in, const int* in_sizes, int n_in,
                              void* d_out, int out_size, void* d_ws, size_t ws_size,
                              hipStream_t stream) {
    const float* gt = (const float*)d_in[0];       // [B, 32, 4] f32
    const float* anchors = (const float*)d_in[1];  // [A, 4] f32
    float* out = (float*)d_out;
    float* highest = (float*)d_ws;                 // [B*32] f32

    const int B = in_sizes[0] / (GT_PER_IMG * 4);
    const int A = in_sizes[1] / 4;

    hipMemsetAsync(highest, 0, (size_t)B * GT_PER_IMG * sizeof(float), stream);

    dim3 g1(64, B);
    k_highest<<<g1, 256, 0, stream>>>(gt, anchors, highest, A);

    const int nblk = (A + 255) / 256;
    k_label<<<nblk, 256, 0, stream>>>(gt, anchors, highest, out, A, B);
}